// Round 3
// baseline (1157.981 us; speedup 1.0000x reference)
//
#include <hip/hip_runtime.h>
#include <hip/hip_bf16.h>

#define BB 8
#define NN 4096
#define BN (BB*NN)
#define KK 10
#define HID 128
#define EPS 1e-5f
#define SLOPE 0.2f

__device__ __forceinline__ float wred_sum64(float v){
  #pragma unroll
  for (int m = 32; m >= 1; m >>= 1) v += __shfl_xor(v, m);
  return v;
}

__device__ __forceinline__ float lrelu(float v){ return v > 0.f ? v : SLOPE * v; }

// ---------------- encoder: x = LN(relu(phys@W+b))*g+b + silu(lat*temW+temb) ----
__global__ __launch_bounds__(256) void encoder_kernel(
    const float* __restrict__ obs, const float* __restrict__ encW,
    const float* __restrict__ encB, const float* __restrict__ lng,
    const float* __restrict__ lnb, const float* __restrict__ temW,
    const float* __restrict__ temB, float* __restrict__ x)
{
  int wave = threadIdx.x >> 6, lane = threadIdx.x & 63;
  int n = blockIdx.x * 4 + wave;
  const float* o = obs + (size_t)n * 10;
  float ph[9];
  #pragma unroll
  for (int k = 0; k < 9; ++k) ph[k] = o[k];
  float lat = o[9];
  int c0 = lane, c1 = lane + 64;
  float a0 = encB[c0], a1 = encB[c1];
  #pragma unroll
  for (int k = 0; k < 9; ++k){
    a0 = fmaf(ph[k], encW[k*HID + c0], a0);
    a1 = fmaf(ph[k], encW[k*HID + c1], a1);
  }
  a0 = fmaxf(a0, 0.f); a1 = fmaxf(a1, 0.f);
  float mean = wred_sum64(a0 + a1) * (1.f/HID);
  float d0 = a0 - mean, d1 = a1 - mean;
  float var = wred_sum64(d0*d0 + d1*d1) * (1.f/HID);
  float rs = rsqrtf(var + EPS);
  float r0 = d0*rs*lng[c0] + lnb[c0];
  float r1 = d1*rs*lng[c1] + lnb[c1];
  float z0 = fmaf(lat, temW[c0], temB[c0]);
  float z1 = fmaf(lat, temW[c1], temB[c1]);
  r0 += z0 / (1.f + __expf(-z0));
  r1 += z1 / (1.f + __expf(-z1));
  x[(size_t)n*HID + c0] = r0;
  x[(size_t)n*HID + c1] = r1;
}

// ---------------- kNN: per-node top-10 nearest within batch -------------------
// 256 threads/block: 4 chunks of 64 nodes share one LDS position staging.
// LDS 48KB/block -> 3 blocks/CU -> 12 waves/CU (vs 3 with 64-thr blocks).
__global__ __launch_bounds__(256) void knn_kernel(
    const float* __restrict__ obs, int* __restrict__ nbr)
{
  __shared__ float px[NN], py[NN], pz[NN];
  int b = blockIdx.x >> 4;
  int chunk4 = blockIdx.x & 15;
  int tid = threadIdx.x;
  size_t boff = (size_t)b * NN;
  for (int j = tid; j < NN; j += 256){
    const float* o = obs + (boff + j) * 10;
    px[j] = o[0]; py[j] = o[1]; pz[j] = o[2];
  }
  __syncthreads();
  int i = chunk4 * 256 + tid;
  float xi = px[i], yi = py[i], zi = pz[i];
  float dk[KK]; int ik[KK];
  #pragma unroll
  for (int k = 0; k < KK; ++k){ dk[k] = 3e38f; ik[k] = 0; }
  for (int j = 0; j < NN; ++j){
    float dx = __fsub_rn(xi, px[j]);
    float dy = __fsub_rn(yi, py[j]);
    float dz = __fsub_rn(zi, pz[j]);
    // match XLA association, block FMA contraction
    float d2 = __fadd_rn(__fadd_rn(__fmul_rn(dx,dx), __fmul_rn(dy,dy)), __fmul_rn(dz,dz));
    if (d2 < dk[KK-1] && j != i){
      float cd = d2; int ci = j;
      #pragma unroll
      for (int k = 0; k < KK; ++k){
        bool lt = cd < dk[k];
        float td = dk[k]; int ti = ik[k];
        dk[k] = lt ? cd : td; ik[k] = lt ? ci : ti;
        cd = lt ? td : cd;   ci = lt ? ti : ci;
      }
    }
  }
  int gi = (int)boff + i;
  #pragma unroll
  for (int k = 0; k < KK; ++k) nbr[(size_t)gi*KK + k] = (int)boff + ik[k];
}

// ---------------- CSR inversion --------------------------------------------
__global__ __launch_bounds__(256) void zero_kernel(int* __restrict__ a, int* __restrict__ b){
  int t = blockIdx.x * 256 + threadIdx.x;
  if (t < BN){ a[t] = 0; b[t] = 0; }
}

__global__ __launch_bounds__(256) void count_kernel(const int* __restrict__ nbr, int* __restrict__ deg){
  int t = blockIdx.x * 256 + threadIdx.x;
  if (t < BN*KK) atomicAdd(&deg[nbr[t]], 1);
}

__global__ __launch_bounds__(1024) void scan_kernel(const int* __restrict__ deg, int* __restrict__ offs){
  __shared__ int part[1024];
  int t = threadIdx.x;
  int base = t * 32;
  int loc[32];
  int s = 0;
  #pragma unroll
  for (int j = 0; j < 32; ++j){ loc[j] = s; s += deg[base + j]; }
  part[t] = s;
  __syncthreads();
  for (int off = 1; off < 1024; off <<= 1){
    int v = (t >= off) ? part[t - off] : 0;
    __syncthreads();
    part[t] += v;
    __syncthreads();
  }
  int prev = (t > 0) ? part[t-1] : 0;
  #pragma unroll
  for (int j = 0; j < 32; ++j) offs[base + j] = prev + loc[j];
  if (t == 1023) offs[BN] = part[1023];
}

__global__ __launch_bounds__(256) void scatter_kernel(
    const int* __restrict__ nbr, const int* __restrict__ offs,
    int* __restrict__ cursor, int* __restrict__ srcs)
{
  int t = blockIdx.x * 256 + threadIdx.x;
  if (t < BN*KK){
    int i = t / KK;
    int d = nbr[t];
    int p = atomicAdd(&cursor[d], 1);
    srcs[offs[d] + p] = i;
  }
}

// ---------------- GAT transform: h = x@W; as_/ad_ projections ----------------
__global__ __launch_bounds__(256) void gat_transform_kernel(
    const float* __restrict__ x, const float* __restrict__ W,
    const float* __restrict__ asrc, const float* __restrict__ adst,
    float* __restrict__ h, float* __restrict__ att)
{
  __shared__ float xs[32][HID];
  int tid = threadIdx.x;
  int node0 = blockIdx.x * 32;
  for (int idx = tid; idx < 32*HID; idx += 256){
    int r = idx >> 7, c = idx & 127;
    xs[r][c] = x[(size_t)(node0 + r)*HID + c];
  }
  __syncthreads();
  int wave = tid >> 6, lane = tid & 63;
  int c0 = lane, c1 = lane + 64;
  float acc[8][2];
  #pragma unroll
  for (int r = 0; r < 8; ++r){ acc[r][0] = 0.f; acc[r][1] = 0.f; }
  for (int k = 0; k < HID; ++k){
    float w0 = W[k*HID + c0], w1 = W[k*HID + c1];
    #pragma unroll
    for (int r = 0; r < 8; ++r){
      float xv = xs[wave*8 + r][k];
      acc[r][0] = fmaf(xv, w0, acc[r][0]);
      acc[r][1] = fmaf(xv, w1, acc[r][1]);
    }
  }
  float asc0 = asrc[c0], asc1 = asrc[c1], adc0 = adst[c0], adc1 = adst[c1];
  #pragma unroll
  for (int r = 0; r < 8; ++r){
    int n = node0 + wave*8 + r;
    float h0 = acc[r][0], h1 = acc[r][1];
    h[(size_t)n*HID + c0] = h0;
    h[(size_t)n*HID + c1] = h1;
    float pas0 = h0*asc0, pas1 = h1*asc1, pad0 = h0*adc0, pad1 = h1*adc1;
    #pragma unroll
    for (int m = 16; m >= 1; m >>= 1){
      pas0 += __shfl_xor(pas0, m); pas1 += __shfl_xor(pas1, m);
      pad0 += __shfl_xor(pad0, m); pad1 += __shfl_xor(pad1, m);
    }
    if ((lane & 31) == 0){
      int hd = lane >> 5;
      att[(size_t)n*8 + hd]     = pas0;   // as_ heads 0/1
      att[(size_t)n*8 + 2 + hd] = pas1;   // as_ heads 2/3
      att[(size_t)n*8 + 4 + hd] = pad0;   // ad_ heads 0/1
      att[(size_t)n*8 + 6 + hd] = pad1;   // ad_ heads 2/3
    }
  }
}

// ---------------- GAT aggregate + bias + LN + relu ---------------------------
__global__ __launch_bounds__(256) void gat_aggregate_kernel(
    const float* __restrict__ h, const float* __restrict__ att,
    const int* __restrict__ offs, const int* __restrict__ deg,
    const int* __restrict__ srcs, const float* __restrict__ bias,
    const float* __restrict__ lng, const float* __restrict__ lnb,
    float* __restrict__ xo)
{
  int wave = threadIdx.x >> 6, lane = threadIdx.x & 63;
  int j = blockIdx.x * 4 + wave;
  int dg = deg[j], base = offs[j];
  float4 adj = *(const float4*)(att + (size_t)j*8 + 4);
  // pass 1: per-head max over incoming edges + self loop (index dg)
  float m0 = -3e38f, m1 = -3e38f, m2 = -3e38f, m3 = -3e38f;
  for (int s0 = 0; s0 <= dg; s0 += 64){
    int s = s0 + lane;
    if (s <= dg){
      int src = (s == dg) ? j : srcs[base + s];
      float4 a = *(const float4*)(att + (size_t)src*8);
      m0 = fmaxf(m0, lrelu(a.x + adj.x));
      m1 = fmaxf(m1, lrelu(a.y + adj.y));
      m2 = fmaxf(m2, lrelu(a.z + adj.z));
      m3 = fmaxf(m3, lrelu(a.w + adj.w));
    }
  }
  #pragma unroll
  for (int m = 32; m >= 1; m >>= 1){
    m0 = fmaxf(m0, __shfl_xor(m0, m));
    m1 = fmaxf(m1, __shfl_xor(m1, m));
    m2 = fmaxf(m2, __shfl_xor(m2, m));
    m3 = fmaxf(m3, __shfl_xor(m3, m));
  }
  int hsel = lane >> 5;
  float mh0 = hsel ? m1 : m0;
  float mh1 = hsel ? m3 : m2;
  float adh0 = hsel ? adj.y : adj.x;
  float adh1 = hsel ? adj.w : adj.z;
  int c0 = lane, c1 = lane + 64;
  float acc0 = 0.f, acc1 = 0.f, den0 = 0.f, den1 = 0.f;
  for (int s = 0; s <= dg; ++s){
    int src = (s == dg) ? j : srcs[base + s];
    const float* ap = att + (size_t)src*8;
    float as0 = ap[hsel];
    float as1 = ap[2 + hsel];
    float w0 = __expf(lrelu(as0 + adh0) - mh0);
    float w1 = __expf(lrelu(as1 + adh1) - mh1);
    den0 += w0; den1 += w1;
    const float* hp = h + (size_t)src*HID;
    acc0 = fmaf(w0, hp[c0], acc0);
    acc1 = fmaf(w1, hp[c1], acc1);
  }
  float o0 = acc0/den0 + bias[c0];
  float o1 = acc1/den1 + bias[c1];
  float mean = wred_sum64(o0 + o1) * (1.f/HID);
  float d0 = o0 - mean, d1 = o1 - mean;
  float var = wred_sum64(d0*d0 + d1*d1) * (1.f/HID);
  float rs = rsqrtf(var + EPS);
  float r0 = fmaxf(fmaf(d0*rs, lng[c0], lnb[c0]), 0.f);
  float r1 = fmaxf(fmaf(d1*rs, lng[c1], lnb[c1]), 0.f);
  xo[(size_t)j*HID + c0] = r0;
  xo[(size_t)j*HID + c1] = r1;
}

// ---------------- heads: actor tanh(relu(xW1+b1)W2+b2), critic ----------------
__global__ __launch_bounds__(256) void heads_kernel(
    const float* __restrict__ x,
    const float* __restrict__ aW1, const float* __restrict__ ab1,
    const float* __restrict__ aW2, const float* __restrict__ ab2,
    const float* __restrict__ cW1, const float* __restrict__ cb1,
    const float* __restrict__ cW2, const float* __restrict__ cb2,
    float* __restrict__ out)
{
  __shared__ float xs[32][HID];
  int tid = threadIdx.x;
  int node0 = blockIdx.x * 32;
  for (int idx = tid; idx < 32*HID; idx += 256){
    int r = idx >> 7, c = idx & 127;
    xs[r][c] = x[(size_t)(node0 + r)*HID + c];
  }
  __syncthreads();
  int wave = tid >> 6, lane = tid & 63;
  int c0 = lane, c1 = lane + 64;
  float aacc[8][2], cacc[8][2];
  #pragma unroll
  for (int r = 0; r < 8; ++r){ aacc[r][0]=0.f; aacc[r][1]=0.f; cacc[r][0]=0.f; cacc[r][1]=0.f; }
  for (int k = 0; k < HID; ++k){
    float aw0 = aW1[k*HID + c0], aw1 = aW1[k*HID + c1];
    float cw0 = cW1[k*HID + c0], cw1 = cW1[k*HID + c1];
    #pragma unroll
    for (int r = 0; r < 8; ++r){
      float xv = xs[wave*8 + r][k];
      aacc[r][0] = fmaf(xv, aw0, aacc[r][0]);
      aacc[r][1] = fmaf(xv, aw1, aacc[r][1]);
      cacc[r][0] = fmaf(xv, cw0, cacc[r][0]);
      cacc[r][1] = fmaf(xv, cw1, cacc[r][1]);
    }
  }
  float ab1_0 = ab1[c0], ab1_1 = ab1[c1], cb1_0 = cb1[c0], cb1_1 = cb1[c1];
  float aw2_00 = aW2[c0*3+0], aw2_01 = aW2[c0*3+1], aw2_02 = aW2[c0*3+2];
  float aw2_10 = aW2[c1*3+0], aw2_11 = aW2[c1*3+1], aw2_12 = aW2[c1*3+2];
  float cw2_0 = cW2[c0], cw2_1 = cW2[c1];
  #pragma unroll
  for (int r = 0; r < 8; ++r){
    int n = node0 + wave*8 + r;
    float h0 = fmaxf(aacc[r][0] + ab1_0, 0.f);
    float h1 = fmaxf(aacc[r][1] + ab1_1, 0.f);
    float g0 = fmaxf(cacc[r][0] + cb1_0, 0.f);
    float g1 = fmaxf(cacc[r][1] + cb1_1, 0.f);
    float p0 = h0*aw2_00 + h1*aw2_10;
    float p1 = h0*aw2_01 + h1*aw2_11;
    float p2 = h0*aw2_02 + h1*aw2_12;
    float pv = g0*cw2_0 + g1*cw2_1;
    #pragma unroll
    for (int m = 32; m >= 1; m >>= 1){
      p0 += __shfl_xor(p0, m);
      p1 += __shfl_xor(p1, m);
      p2 += __shfl_xor(p2, m);
      pv += __shfl_xor(pv, m);
    }
    if (lane == 0){
      out[(size_t)n*3 + 0] = tanhf(p0 + ab2[0]);
      out[(size_t)n*3 + 1] = tanhf(p1 + ab2[1]);
      out[(size_t)n*3 + 2] = tanhf(p2 + ab2[2]);
      out[(size_t)BN*3 + n] = pv + cb2[0];
    }
  }
}

extern "C" void kernel_launch(void* const* d_in, const int* in_sizes, int n_in,
                              void* d_out, int out_size, void* d_ws, size_t ws_size,
                              hipStream_t stream) {
  const float* obs  = (const float*)d_in[0];
  const float* encW = (const float*)d_in[1];
  const float* encB = (const float*)d_in[2];
  const float* elng = (const float*)d_in[3];
  const float* elnb = (const float*)d_in[4];
  const float* temW = (const float*)d_in[5];
  const float* temB = (const float*)d_in[6];
  const float* aW1  = (const float*)d_in[7];
  const float* ab1  = (const float*)d_in[8];
  const float* aW2  = (const float*)d_in[9];
  const float* ab2  = (const float*)d_in[10];
  const float* cW1  = (const float*)d_in[11];
  const float* cb1  = (const float*)d_in[12];
  const float* cW2  = (const float*)d_in[13];
  const float* cb2  = (const float*)d_in[14];
  const float* gW[2]   = {(const float*)d_in[15], (const float*)d_in[21]};
  const float* gas[2]  = {(const float*)d_in[16], (const float*)d_in[22]};
  const float* gad[2]  = {(const float*)d_in[17], (const float*)d_in[23]};
  const float* gb[2]   = {(const float*)d_in[18], (const float*)d_in[24]};
  const float* glng[2] = {(const float*)d_in[19], (const float*)d_in[25]};
  const float* glnb[2] = {(const float*)d_in[20], (const float*)d_in[26]};

  float* x   = (float*)d_ws;
  float* h   = x + (size_t)BN*HID;
  float* att = h + (size_t)BN*HID;
  int* nbr    = (int*)(att + (size_t)BN*8);
  int* deg    = nbr + (size_t)BN*KK;
  int* cursor = deg + BN;
  int* offs   = cursor + BN;
  int* srcs   = offs + BN + 1;

  encoder_kernel<<<BN/4, 256, 0, stream>>>(obs, encW, encB, elng, elnb, temW, temB, x);
  knn_kernel<<<BB*16, 256, 0, stream>>>(obs, nbr);
  zero_kernel<<<BN/256, 256, 0, stream>>>(deg, cursor);
  count_kernel<<<(BN*KK)/256, 256, 0, stream>>>(nbr, deg);
  scan_kernel<<<1, 1024, 0, stream>>>(deg, offs);
  scatter_kernel<<<(BN*KK)/256, 256, 0, stream>>>(nbr, offs, cursor, srcs);

  for (int l = 0; l < 2; ++l){
    gat_transform_kernel<<<BN/32, 256, 0, stream>>>(x, gW[l], gas[l], gad[l], h, att);
    gat_aggregate_kernel<<<BN/4, 256, 0, stream>>>(h, att, offs, deg, srcs,
                                                   gb[l], glng[l], glnb[l], x);
  }

  heads_kernel<<<BN/32, 256, 0, stream>>>(x, aW1, ab1, aW2, ab2, cW1, cb1, cW2, cb2,
                                          (float*)d_out);
}

// Round 6
// 885.624 us; speedup vs baseline: 1.3075x; 1.3075x over previous
//
#include <hip/hip_runtime.h>
#include <hip/hip_bf16.h>

#define BB 8
#define NN 4096
#define BN (BB*NN)
#define KK 10
#define HID 128
#define EPS 1e-5f
#define SLOPE 0.2f

__device__ __forceinline__ float wred_sum64(float v){
  #pragma unroll
  for (int m = 32; m >= 1; m >>= 1) v += __shfl_xor(v, m);
  return v;
}

__device__ __forceinline__ float lrelu(float v){ return v > 0.f ? v : SLOPE * v; }

// ---------------- encoder: x = LN(relu(phys@W+b))*g+b + silu(lat*temW+temb) ----
// also packs positions into pos4 (x,y,z,0) for the kNN kernel
__global__ __launch_bounds__(256) void encoder_kernel(
    const float* __restrict__ obs, const float* __restrict__ encW,
    const float* __restrict__ encB, const float* __restrict__ lng,
    const float* __restrict__ lnb, const float* __restrict__ temW,
    const float* __restrict__ temB, float* __restrict__ x,
    float4* __restrict__ pos4)
{
  int wave = threadIdx.x >> 6, lane = threadIdx.x & 63;
  int n = blockIdx.x * 4 + wave;
  const float* o = obs + (size_t)n * 10;
  float ph[9];
  #pragma unroll
  for (int k = 0; k < 9; ++k) ph[k] = o[k];
  float lat = o[9];
  if (lane == 0) pos4[n] = make_float4(ph[0], ph[1], ph[2], 0.f);
  int c0 = lane, c1 = lane + 64;
  float a0 = encB[c0], a1 = encB[c1];
  #pragma unroll
  for (int k = 0; k < 9; ++k){
    a0 = fmaf(ph[k], encW[k*HID + c0], a0);
    a1 = fmaf(ph[k], encW[k*HID + c1], a1);
  }
  a0 = fmaxf(a0, 0.f); a1 = fmaxf(a1, 0.f);
  float mean = wred_sum64(a0 + a1) * (1.f/HID);
  float d0 = a0 - mean, d1 = a1 - mean;
  float var = wred_sum64(d0*d0 + d1*d1) * (1.f/HID);
  float rs = rsqrtf(var + EPS);
  float r0 = d0*rs*lng[c0] + lnb[c0];
  float r1 = d1*rs*lng[c1] + lnb[c1];
  float z0 = fmaf(lat, temW[c0], temB[c0]);
  float z1 = fmaf(lat, temW[c1], temB[c1]);
  r0 += z0 / (1.f + __expf(-z0));
  r1 += z1 / (1.f + __expf(-z1));
  x[(size_t)n*HID + c0] = r0;
  x[(size_t)n*HID + c1] = r1;
}

// ---------------- kNN: 8 lanes per node, lexicographic (d2, idx) top-10 -------
// block = 256 thr = 32 nodes x 8 sub-lanes; each sub-lane scans 512 candidates
// staged in LDS as transposed float4 groups (3 x ds_read_b128 per 4 candidates),
// XOR-swizzled so the 8 sub-lanes hit 8 distinct bank quads (conflict-free).
__global__ __launch_bounds__(256) void knn_kernel(
    const float4* __restrict__ pos4, int* __restrict__ nbr)
{
  __shared__ float4 X4[1024], Y4[1024], Z4[1024];
  int bi = blockIdx.x;
  int b  = bi >> 7;          // 128 blocks per batch
  int nb = bi & 127;
  int tid = threadIdx.x;
  size_t boff = (size_t)b * NN;
  for (int p = tid; p < 1024; p += 256){
    const float4* srcp = pos4 + boff + 4*(size_t)p;
    float4 a = srcp[0], c = srcp[1], d = srcp[2], e = srcp[3];
    int slot = p ^ ((p >> 7) & 7);
    X4[slot] = make_float4(a.x, c.x, d.x, e.x);
    Y4[slot] = make_float4(a.y, c.y, d.y, e.y);
    Z4[slot] = make_float4(a.z, c.z, d.z, e.z);
  }
  __syncthreads();
  int g = tid >> 3, s = tid & 7;
  int i = nb * 32 + g;                 // node index within batch
  float4 me = pos4[boff + i];
  float xi = me.x, yi = me.y, zi = me.z;
  float dk[KK]; int ik[KK];
  #pragma unroll
  for (int k = 0; k < KK; ++k){ dk[k] = 3e38f; ik[k] = 0x7fffffff; }
  for (int q = 0; q < 128; ++q){
    int p = (s << 7) | q;
    int slot = p ^ s;
    float4 X = X4[slot], Y = Y4[slot], Z = Z4[slot];
    int jb = p << 2;
    #pragma unroll
    for (int c = 0; c < 4; ++c){
      float cx = c==0?X.x:c==1?X.y:c==2?X.z:X.w;
      float cy = c==0?Y.x:c==1?Y.y:c==2?Y.z:Y.w;
      float cz = c==0?Z.x:c==1?Z.y:c==2?Z.z:Z.w;
      int j = jb + c;
      float dx = __fsub_rn(xi, cx);
      float dy = __fsub_rn(yi, cy);
      float dz = __fsub_rn(zi, cz);
      float d2 = __fadd_rn(__fadd_rn(__fmul_rn(dx,dx), __fmul_rn(dy,dy)), __fmul_rn(dz,dz));
      bool enter = (j != i) && ((d2 < dk[KK-1]) || (d2 == dk[KK-1] && j < ik[KK-1]));
      if (enter){
        float cd = d2; int ci = j;
        #pragma unroll
        for (int k = 0; k < KK; ++k){
          bool lt = (cd < dk[k]) || (cd == dk[k] && ci < ik[k]);
          float td = dk[k]; int ti = ik[k];
          dk[k] = lt ? cd : td; ik[k] = lt ? ci : ti;
          cd = lt ? td : cd;   ci = lt ? ti : ci;
        }
      }
    }
  }
  // merge 8 sorted lists via 10 rounds of min-lex reduce over the 8 sub-lanes
  int gi = (int)boff + i;
  for (int r = 0; r < KK; ++r){
    float d0 = dk[0]; int i0 = ik[0];
    #pragma unroll
    for (int m = 1; m <= 4; m <<= 1){
      float od = __shfl_xor(d0, m); int oi = __shfl_xor(i0, m);
      bool take = (od < d0) || (od == d0 && oi < i0);
      d0 = take ? od : d0; i0 = take ? oi : i0;
    }
    bool win = (dk[0] == d0) && (ik[0] == i0);
    if (win){
      #pragma unroll
      for (int k = 0; k < KK-1; ++k){ dk[k] = dk[k+1]; ik[k] = ik[k+1]; }
      dk[KK-1] = 3e38f; ik[KK-1] = 0x7fffffff;
    }
    if (s == 0) nbr[(size_t)gi*KK + r] = (int)boff + i0;
  }
}

// ---------------- CSR inversion --------------------------------------------
__global__ __launch_bounds__(256) void zero_kernel(int* __restrict__ a, int* __restrict__ b){
  int t = blockIdx.x * 256 + threadIdx.x;
  if (t < BN){ a[t] = 0; b[t] = 0; }
}

__global__ __launch_bounds__(256) void count_kernel(const int* __restrict__ nbr, int* __restrict__ deg){
  int t = blockIdx.x * 256 + threadIdx.x;
  if (t < BN*KK) atomicAdd(&deg[nbr[t]], 1);
}

__global__ __launch_bounds__(1024) void scan_kernel(const int* __restrict__ deg, int* __restrict__ offs){
  __shared__ int part[1024];
  int t = threadIdx.x;
  int base = t * 32;
  int loc[32];
  int s = 0;
  #pragma unroll
  for (int j = 0; j < 32; ++j){ loc[j] = s; s += deg[base + j]; }
  part[t] = s;
  __syncthreads();
  for (int off = 1; off < 1024; off <<= 1){
    int v = (t >= off) ? part[t - off] : 0;
    __syncthreads();
    part[t] += v;
    __syncthreads();
  }
  int prev = (t > 0) ? part[t-1] : 0;
  #pragma unroll
  for (int j = 0; j < 32; ++j) offs[base + j] = prev + loc[j];
  if (t == 1023) offs[BN] = part[1023];
}

__global__ __launch_bounds__(256) void scatter_kernel(
    const int* __restrict__ nbr, const int* __restrict__ offs,
    int* __restrict__ cursor, int* __restrict__ srcs)
{
  int t = blockIdx.x * 256 + threadIdx.x;
  if (t < BN*KK){
    int i = t / KK;
    int d = nbr[t];
    int p = atomicAdd(&cursor[d], 1);
    srcs[offs[d] + p] = i;
  }
}

// ---------------- GAT transform: h = x@W; as_/ad_ projections ----------------
__global__ __launch_bounds__(256) void gat_transform_kernel(
    const float* __restrict__ x, const float* __restrict__ W,
    const float* __restrict__ asrc, const float* __restrict__ adst,
    float* __restrict__ h, float* __restrict__ att)
{
  __shared__ float xs[32][HID];
  int tid = threadIdx.x;
  int node0 = blockIdx.x * 32;
  for (int idx = tid; idx < 32*HID; idx += 256){
    int r = idx >> 7, c = idx & 127;
    xs[r][c] = x[(size_t)(node0 + r)*HID + c];
  }
  __syncthreads();
  int wave = tid >> 6, lane = tid & 63;
  int c0 = lane, c1 = lane + 64;
  float acc[8][2];
  #pragma unroll
  for (int r = 0; r < 8; ++r){ acc[r][0] = 0.f; acc[r][1] = 0.f; }
  for (int k = 0; k < HID; ++k){
    float w0 = W[k*HID + c0], w1 = W[k*HID + c1];
    #pragma unroll
    for (int r = 0; r < 8; ++r){
      float xv = xs[wave*8 + r][k];
      acc[r][0] = fmaf(xv, w0, acc[r][0]);
      acc[r][1] = fmaf(xv, w1, acc[r][1]);
    }
  }
  float asc0 = asrc[c0], asc1 = asrc[c1], adc0 = adst[c0], adc1 = adst[c1];
  #pragma unroll
  for (int r = 0; r < 8; ++r){
    int n = node0 + wave*8 + r;
    float h0 = acc[r][0], h1 = acc[r][1];
    h[(size_t)n*HID + c0] = h0;
    h[(size_t)n*HID + c1] = h1;
    float pas0 = h0*asc0, pas1 = h1*asc1, pad0 = h0*adc0, pad1 = h1*adc1;
    #pragma unroll
    for (int m = 16; m >= 1; m >>= 1){
      pas0 += __shfl_xor(pas0, m); pas1 += __shfl_xor(pas1, m);
      pad0 += __shfl_xor(pad0, m); pad1 += __shfl_xor(pad1, m);
    }
    if ((lane & 31) == 0){
      int hd = lane >> 5;
      att[(size_t)n*8 + hd]     = pas0;   // as_ heads 0/1
      att[(size_t)n*8 + 2 + hd] = pas1;   // as_ heads 2/3
      att[(size_t)n*8 + 4 + hd] = pad0;   // ad_ heads 0/1
      att[(size_t)n*8 + 6 + hd] = pad1;   // ad_ heads 2/3
    }
  }
}

// ---------------- GAT aggregate + bias + LN + relu ---------------------------
__global__ __launch_bounds__(256) void gat_aggregate_kernel(
    const float* __restrict__ h, const float* __restrict__ att,
    const int* __restrict__ offs, const int* __restrict__ deg,
    const int* __restrict__ srcs, const float* __restrict__ bias,
    const float* __restrict__ lng, const float* __restrict__ lnb,
    float* __restrict__ xo)
{
  int wave = threadIdx.x >> 6, lane = threadIdx.x & 63;
  int j = blockIdx.x * 4 + wave;
  int dg = deg[j], base = offs[j];
  float4 adj = *(const float4*)(att + (size_t)j*8 + 4);
  // pass 1: per-head max over incoming edges + self loop (index dg)
  float m0 = -3e38f, m1 = -3e38f, m2 = -3e38f, m3 = -3e38f;
  for (int s0 = 0; s0 <= dg; s0 += 64){
    int s = s0 + lane;
    if (s <= dg){
      int src = (s == dg) ? j : srcs[base + s];
      float4 a = *(const float4*)(att + (size_t)src*8);
      m0 = fmaxf(m0, lrelu(a.x + adj.x));
      m1 = fmaxf(m1, lrelu(a.y + adj.y));
      m2 = fmaxf(m2, lrelu(a.z + adj.z));
      m3 = fmaxf(m3, lrelu(a.w + adj.w));
    }
  }
  #pragma unroll
  for (int m = 32; m >= 1; m >>= 1){
    m0 = fmaxf(m0, __shfl_xor(m0, m));
    m1 = fmaxf(m1, __shfl_xor(m1, m));
    m2 = fmaxf(m2, __shfl_xor(m2, m));
    m3 = fmaxf(m3, __shfl_xor(m3, m));
  }
  int hsel = lane >> 5;
  float mh0 = hsel ? m1 : m0;
  float mh1 = hsel ? m3 : m2;
  float adh0 = hsel ? adj.y : adj.x;
  float adh1 = hsel ? adj.w : adj.z;
  int c0 = lane, c1 = lane + 64;
  float acc0 = 0.f, acc1 = 0.f, den0 = 0.f, den1 = 0.f;
  for (int s = 0; s <= dg; ++s){
    int src = (s == dg) ? j : srcs[base + s];
    const float* ap = att + (size_t)src*8;
    float as0 = ap[hsel];
    float as1 = ap[2 + hsel];
    float w0 = __expf(lrelu(as0 + adh0) - mh0);
    float w1 = __expf(lrelu(as1 + adh1) - mh1);
    den0 += w0; den1 += w1;
    const float* hp = h + (size_t)src*HID;
    acc0 = fmaf(w0, hp[c0], acc0);
    acc1 = fmaf(w1, hp[c1], acc1);
  }
  float o0 = acc0/den0 + bias[c0];
  float o1 = acc1/den1 + bias[c1];
  float mean = wred_sum64(o0 + o1) * (1.f/HID);
  float d0 = o0 - mean, d1 = o1 - mean;
  float var = wred_sum64(d0*d0 + d1*d1) * (1.f/HID);
  float rs = rsqrtf(var + EPS);
  float r0 = fmaxf(fmaf(d0*rs, lng[c0], lnb[c0]), 0.f);
  float r1 = fmaxf(fmaf(d1*rs, lng[c1], lnb[c1]), 0.f);
  xo[(size_t)j*HID + c0] = r0;
  xo[(size_t)j*HID + c1] = r1;
}

// ---------------- heads: actor tanh(relu(xW1+b1)W2+b2), critic ----------------
__global__ __launch_bounds__(256) void heads_kernel(
    const float* __restrict__ x,
    const float* __restrict__ aW1, const float* __restrict__ ab1,
    const float* __restrict__ aW2, const float* __restrict__ ab2,
    const float* __restrict__ cW1, const float* __restrict__ cb1,
    const float* __restrict__ cW2, const float* __restrict__ cb2,
    float* __restrict__ out)
{
  __shared__ float xs[32][HID];
  int tid = threadIdx.x;
  int node0 = blockIdx.x * 32;
  for (int idx = tid; idx < 32*HID; idx += 256){
    int r = idx >> 7, c = idx & 127;
    xs[r][c] = x[(size_t)(node0 + r)*HID + c];
  }
  __syncthreads();
  int wave = tid >> 6, lane = tid & 63;
  int c0 = lane, c1 = lane + 64;
  float aacc[8][2], cacc[8][2];
  #pragma unroll
  for (int r = 0; r < 8; ++r){ aacc[r][0]=0.f; aacc[r][1]=0.f; cacc[r][0]=0.f; cacc[r][1]=0.f; }
  for (int k = 0; k < HID; ++k){
    float aw0 = aW1[k*HID + c0], aw1 = aW1[k*HID + c1];
    float cw0 = cW1[k*HID + c0], cw1 = cW1[k*HID + c1];
    #pragma unroll
    for (int r = 0; r < 8; ++r){
      float xv = xs[wave*8 + r][k];
      aacc[r][0] = fmaf(xv, aw0, aacc[r][0]);
      aacc[r][1] = fmaf(xv, aw1, aacc[r][1]);
      cacc[r][0] = fmaf(xv, cw0, cacc[r][0]);
      cacc[r][1] = fmaf(xv, cw1, cacc[r][1]);
    }
  }
  float ab1_0 = ab1[c0], ab1_1 = ab1[c1], cb1_0 = cb1[c0], cb1_1 = cb1[c1];
  float aw2_00 = aW2[c0*3+0], aw2_01 = aW2[c0*3+1], aw2_02 = aW2[c0*3+2];
  float aw2_10 = aW2[c1*3+0], aw2_11 = aW2[c1*3+1], aw2_12 = aW2[c1*3+2];
  float cw2_0 = cW2[c0], cw2_1 = cW2[c1];
  #pragma unroll
  for (int r = 0; r < 8; ++r){
    int n = node0 + wave*8 + r;
    float h0 = fmaxf(aacc[r][0] + ab1_0, 0.f);
    float h1 = fmaxf(aacc[r][1] + ab1_1, 0.f);
    float g0 = fmaxf(cacc[r][0] + cb1_0, 0.f);
    float g1 = fmaxf(cacc[r][1] + cb1_1, 0.f);
    float p0 = h0*aw2_00 + h1*aw2_10;
    float p1 = h0*aw2_01 + h1*aw2_11;
    float p2 = h0*aw2_02 + h1*aw2_12;
    float pv = g0*cw2_0 + g1*cw2_1;
    #pragma unroll
    for (int m = 32; m >= 1; m >>= 1){
      p0 += __shfl_xor(p0, m);
      p1 += __shfl_xor(p1, m);
      p2 += __shfl_xor(p2, m);
      pv += __shfl_xor(pv, m);
    }
    if (lane == 0){
      out[(size_t)n*3 + 0] = tanhf(p0 + ab2[0]);
      out[(size_t)n*3 + 1] = tanhf(p1 + ab2[1]);
      out[(size_t)n*3 + 2] = tanhf(p2 + ab2[2]);
      out[(size_t)BN*3 + n] = pv + cb2[0];
    }
  }
}

extern "C" void kernel_launch(void* const* d_in, const int* in_sizes, int n_in,
                              void* d_out, int out_size, void* d_ws, size_t ws_size,
                              hipStream_t stream) {
  const float* obs  = (const float*)d_in[0];
  const float* encW = (const float*)d_in[1];
  const float* encB = (const float*)d_in[2];
  const float* elng = (const float*)d_in[3];
  const float* elnb = (const float*)d_in[4];
  const float* temW = (const float*)d_in[5];
  const float* temB = (const float*)d_in[6];
  const float* aW1  = (const float*)d_in[7];
  const float* ab1  = (const float*)d_in[8];
  const float* aW2  = (const float*)d_in[9];
  const float* ab2  = (const float*)d_in[10];
  const float* cW1  = (const float*)d_in[11];
  const float* cb1  = (const float*)d_in[12];
  const float* cW2  = (const float*)d_in[13];
  const float* cb2  = (const float*)d_in[14];
  const float* gW[2]   = {(const float*)d_in[15], (const float*)d_in[21]};
  const float* gas[2]  = {(const float*)d_in[16], (const float*)d_in[22]};
  const float* gad[2]  = {(const float*)d_in[17], (const float*)d_in[23]};
  const float* gb[2]   = {(const float*)d_in[18], (const float*)d_in[24]};
  const float* glng[2] = {(const float*)d_in[19], (const float*)d_in[25]};
  const float* glnb[2] = {(const float*)d_in[20], (const float*)d_in[26]};

  float* x   = (float*)d_ws;
  float* h   = x + (size_t)BN*HID;
  float* att = h + (size_t)BN*HID;
  float4* pos4 = (float4*)(att + (size_t)BN*8);
  int* nbr    = (int*)(pos4 + BN);
  int* deg    = nbr + (size_t)BN*KK;
  int* cursor = deg + BN;
  int* offs   = cursor + BN;
  int* srcs   = offs + BN + 1;

  encoder_kernel<<<BN/4, 256, 0, stream>>>(obs, encW, encB, elng, elnb, temW, temB, x, pos4);
  knn_kernel<<<BN/32, 256, 0, stream>>>(pos4, nbr);
  zero_kernel<<<BN/256, 256, 0, stream>>>(deg, cursor);
  count_kernel<<<(BN*KK)/256, 256, 0, stream>>>(nbr, deg);
  scan_kernel<<<1, 1024, 0, stream>>>(deg, offs);
  scatter_kernel<<<(BN*KK)/256, 256, 0, stream>>>(nbr, offs, cursor, srcs);

  for (int l = 0; l < 2; ++l){
    gat_transform_kernel<<<BN/32, 256, 0, stream>>>(x, gW[l], gas[l], gad[l], h, att);
    gat_aggregate_kernel<<<BN/4, 256, 0, stream>>>(h, att, offs, deg, srcs,
                                                   gb[l], glng[l], glnb[l], x);
  }

  heads_kernel<<<BN/32, 256, 0, stream>>>(x, aW1, ab1, aW2, ab2, cW1, cb1, cW2, cb2,
                                          (float*)d_out);
}

// Round 9
// 564.610 us; speedup vs baseline: 2.0509x; 1.5686x over previous
//
#include <hip/hip_runtime.h>
#include <hip/hip_bf16.h>

#define BB 8
#define NN 4096
#define BN (BB*NN)
#define KK 10
#define HID 128
#define EPS 1e-5f
#define SLOPE 0.2f

__device__ __forceinline__ float wred_sum64(float v){
  #pragma unroll
  for (int m = 32; m >= 1; m >>= 1) v += __shfl_xor(v, m);
  return v;
}

__device__ __forceinline__ float lrelu(float v){ return v > 0.f ? v : SLOPE * v; }

// ---------------- encoder: x = LN(relu(phys@W+b))*g+b + silu(lat*temW+temb) ----
// also packs positions into pos4 (x,y,z,0) for the kNN kernel
__global__ __launch_bounds__(256) void encoder_kernel(
    const float* __restrict__ obs, const float* __restrict__ encW,
    const float* __restrict__ encB, const float* __restrict__ lng,
    const float* __restrict__ lnb, const float* __restrict__ temW,
    const float* __restrict__ temB, float* __restrict__ x,
    float4* __restrict__ pos4)
{
  int wave = threadIdx.x >> 6, lane = threadIdx.x & 63;
  int n = blockIdx.x * 4 + wave;
  const float* o = obs + (size_t)n * 10;
  float ph[9];
  #pragma unroll
  for (int k = 0; k < 9; ++k) ph[k] = o[k];
  float lat = o[9];
  if (lane == 0) pos4[n] = make_float4(ph[0], ph[1], ph[2], 0.f);
  int c0 = lane, c1 = lane + 64;
  float a0 = encB[c0], a1 = encB[c1];
  #pragma unroll
  for (int k = 0; k < 9; ++k){
    a0 = fmaf(ph[k], encW[k*HID + c0], a0);
    a1 = fmaf(ph[k], encW[k*HID + c1], a1);
  }
  a0 = fmaxf(a0, 0.f); a1 = fmaxf(a1, 0.f);
  float mean = wred_sum64(a0 + a1) * (1.f/HID);
  float d0 = a0 - mean, d1 = a1 - mean;
  float var = wred_sum64(d0*d0 + d1*d1) * (1.f/HID);
  float rs = rsqrtf(var + EPS);
  float r0 = d0*rs*lng[c0] + lnb[c0];
  float r1 = d1*rs*lng[c1] + lnb[c1];
  float z0 = fmaf(lat, temW[c0], temB[c0]);
  float z1 = fmaf(lat, temW[c1], temB[c1]);
  r0 += z0 / (1.f + __expf(-z0));
  r1 += z1 / (1.f + __expf(-z1));
  x[(size_t)n*HID + c0] = r0;
  x[(size_t)n*HID + c1] = r1;
}

// ---------------- kNN v3: 16 sublanes/node, u64 keys, branchless rank-insert --
// block = 256 thr = 16 nodes x 16 sublanes; 2 staged halves of 2048 candidates
// (24KB LDS -> 6 blocks/CU). key = (float_bits(d2)<<32)|j : single u64 compare
// gives exact lexicographic (d2, idx) order == jax top_k tie-breaking.
__global__ __launch_bounds__(256) void knn_kernel(
    const float4* __restrict__ pos4, int* __restrict__ nbr)
{
  __shared__ float4 X4[512], Y4[512], Z4[512];
  int bi = blockIdx.x;
  int b  = bi >> 8;           // 256 blocks per batch
  int nb = bi & 255;
  int tid = threadIdx.x;
  int g = tid >> 4, s = tid & 15;
  size_t boff = (size_t)b * NN;
  int i = nb * 16 + g;        // node index within batch
  float4 me = pos4[boff + i];
  float xi = me.x, yi = me.y, zi = me.z;
  unsigned long long key[KK];
  #pragma unroll
  for (int k = 0; k < KK; ++k) key[k] = ~0ULL;

  for (int h = 0; h < 2; ++h){
    __syncthreads();
    for (int p = tid; p < 512; p += 256){
      const float4* srcp = pos4 + boff + (size_t)(h*2048 + 4*p);
      float4 a = srcp[0], c = srcp[1], d = srcp[2], e = srcp[3];
      int slot = p ^ ((p >> 5) & 7);
      X4[slot] = make_float4(a.x, c.x, d.x, e.x);
      Y4[slot] = make_float4(a.y, c.y, d.y, e.y);
      Z4[slot] = make_float4(a.z, c.z, d.z, e.z);
    }
    __syncthreads();
    for (int q = 0; q < 32; ++q){
      int p = s * 32 + q;
      int slot = p ^ (s & 7);
      float4 X = X4[slot], Y = Y4[slot], Z = Z4[slot];
      int jb = h*2048 + (p << 2);
      #pragma unroll
      for (int cc = 0; cc < 4; ++cc){
        float cx = cc==0?X.x:cc==1?X.y:cc==2?X.z:X.w;
        float cy = cc==0?Y.x:cc==1?Y.y:cc==2?Y.z:Y.w;
        float cz = cc==0?Z.x:cc==1?Z.y:cc==2?Z.z:Z.w;
        int j = jb + cc;
        float dx = __fsub_rn(xi, cx);
        float dy = __fsub_rn(yi, cy);
        float dz = __fsub_rn(zi, cz);
        // match XLA association, block FMA contraction
        float d2 = __fadd_rn(__fadd_rn(__fmul_rn(dx,dx), __fmul_rn(dy,dy)), __fmul_rn(dz,dz));
        unsigned long long ck =
            ((unsigned long long)__float_as_uint(d2) << 32) | (unsigned)j;
        if (j == i) ck = ~0ULL;                 // exclude self (diag +1e10)
        if (ck < key[KK-1]){
          bool lt[KK];
          #pragma unroll
          for (int k = 0; k < KK; ++k) lt[k] = key[k] < ck;   // independent, ILP
          #pragma unroll
          for (int k = KK-1; k >= 1; --k)
            key[k] = lt[k] ? key[k] : (lt[k-1] ? ck : key[k-1]);
          key[0] = lt[0] ? key[0] : ck;
        }
      }
    }
  }
  // merge 16 sublane lists: 10 rounds of min-extract over the 16-lane group
  int gi = (int)boff + i;
  for (int r = 0; r < KK; ++r){
    unsigned long long k0 = key[0];
    #pragma unroll
    for (int m = 1; m <= 8; m <<= 1){
      unsigned long long ok = __shfl_xor(k0, m);
      if (ok < k0) k0 = ok;
    }
    if (key[0] == k0){   // unique winner: keys are unique (idx in low bits)
      #pragma unroll
      for (int k = 0; k < KK-1; ++k) key[k] = key[k+1];
      key[KK-1] = ~0ULL;
    }
    if (s == 0) nbr[(size_t)gi*KK + r] = (int)boff + (int)(unsigned)(k0 & 0xFFFFFFFFULL);
  }
}

// ---------------- CSR inversion --------------------------------------------
__global__ __launch_bounds__(256) void zero_kernel(int* __restrict__ a, int* __restrict__ b){
  int t = blockIdx.x * 256 + threadIdx.x;
  if (t < BN){ a[t] = 0; b[t] = 0; }
}

__global__ __launch_bounds__(256) void count_kernel(const int* __restrict__ nbr, int* __restrict__ deg){
  int t = blockIdx.x * 256 + threadIdx.x;
  if (t < BN*KK) atomicAdd(&deg[nbr[t]], 1);
}

__global__ __launch_bounds__(1024) void scan_kernel(const int* __restrict__ deg, int* __restrict__ offs){
  __shared__ int part[1024];
  int t = threadIdx.x;
  int base = t * 32;
  int loc[32];
  int s = 0;
  #pragma unroll
  for (int j = 0; j < 32; ++j){ loc[j] = s; s += deg[base + j]; }
  part[t] = s;
  __syncthreads();
  for (int off = 1; off < 1024; off <<= 1){
    int v = (t >= off) ? part[t - off] : 0;
    __syncthreads();
    part[t] += v;
    __syncthreads();
  }
  int prev = (t > 0) ? part[t-1] : 0;
  #pragma unroll
  for (int j = 0; j < 32; ++j) offs[base + j] = prev + loc[j];
  if (t == 1023) offs[BN] = part[1023];
}

__global__ __launch_bounds__(256) void scatter_kernel(
    const int* __restrict__ nbr, const int* __restrict__ offs,
    int* __restrict__ cursor, int* __restrict__ srcs)
{
  int t = blockIdx.x * 256 + threadIdx.x;
  if (t < BN*KK){
    int i = t / KK;
    int d = nbr[t];
    int p = atomicAdd(&cursor[d], 1);
    srcs[offs[d] + p] = i;
  }
}

// ---------------- GAT transform: h = x@W; as_/ad_ projections ----------------
__global__ __launch_bounds__(256) void gat_transform_kernel(
    const float* __restrict__ x, const float* __restrict__ W,
    const float* __restrict__ asrc, const float* __restrict__ adst,
    float* __restrict__ h, float* __restrict__ att)
{
  __shared__ float xs[32][HID];
  int tid = threadIdx.x;
  int node0 = blockIdx.x * 32;
  for (int idx = tid; idx < 32*HID; idx += 256){
    int r = idx >> 7, c = idx & 127;
    xs[r][c] = x[(size_t)(node0 + r)*HID + c];
  }
  __syncthreads();
  int wave = tid >> 6, lane = tid & 63;
  int c0 = lane, c1 = lane + 64;
  float acc[8][2];
  #pragma unroll
  for (int r = 0; r < 8; ++r){ acc[r][0] = 0.f; acc[r][1] = 0.f; }
  for (int k = 0; k < HID; ++k){
    float w0 = W[k*HID + c0], w1 = W[k*HID + c1];
    #pragma unroll
    for (int r = 0; r < 8; ++r){
      float xv = xs[wave*8 + r][k];
      acc[r][0] = fmaf(xv, w0, acc[r][0]);
      acc[r][1] = fmaf(xv, w1, acc[r][1]);
    }
  }
  float asc0 = asrc[c0], asc1 = asrc[c1], adc0 = adst[c0], adc1 = adst[c1];
  #pragma unroll
  for (int r = 0; r < 8; ++r){
    int n = node0 + wave*8 + r;
    float h0 = acc[r][0], h1 = acc[r][1];
    h[(size_t)n*HID + c0] = h0;
    h[(size_t)n*HID + c1] = h1;
    float pas0 = h0*asc0, pas1 = h1*asc1, pad0 = h0*adc0, pad1 = h1*adc1;
    #pragma unroll
    for (int m = 16; m >= 1; m >>= 1){
      pas0 += __shfl_xor(pas0, m); pas1 += __shfl_xor(pas1, m);
      pad0 += __shfl_xor(pad0, m); pad1 += __shfl_xor(pad1, m);
    }
    if ((lane & 31) == 0){
      int hd = lane >> 5;
      att[(size_t)n*8 + hd]     = pas0;   // as_ heads 0/1
      att[(size_t)n*8 + 2 + hd] = pas1;   // as_ heads 2/3
      att[(size_t)n*8 + 4 + hd] = pad0;   // ad_ heads 0/1
      att[(size_t)n*8 + 6 + hd] = pad1;   // ad_ heads 2/3
    }
  }
}

// ---------------- GAT aggregate + bias + LN + relu ---------------------------
__global__ __launch_bounds__(256) void gat_aggregate_kernel(
    const float* __restrict__ h, const float* __restrict__ att,
    const int* __restrict__ offs, const int* __restrict__ deg,
    const int* __restrict__ srcs, const float* __restrict__ bias,
    const float* __restrict__ lng, const float* __restrict__ lnb,
    float* __restrict__ xo)
{
  int wave = threadIdx.x >> 6, lane = threadIdx.x & 63;
  int j = blockIdx.x * 4 + wave;
  int dg = deg[j], base = offs[j];
  float4 adj = *(const float4*)(att + (size_t)j*8 + 4);
  // pass 1: per-head max over incoming edges + self loop (index dg)
  float m0 = -3e38f, m1 = -3e38f, m2 = -3e38f, m3 = -3e38f;
  for (int s0 = 0; s0 <= dg; s0 += 64){
    int s = s0 + lane;
    if (s <= dg){
      int src = (s == dg) ? j : srcs[base + s];
      float4 a = *(const float4*)(att + (size_t)src*8);
      m0 = fmaxf(m0, lrelu(a.x + adj.x));
      m1 = fmaxf(m1, lrelu(a.y + adj.y));
      m2 = fmaxf(m2, lrelu(a.z + adj.z));
      m3 = fmaxf(m3, lrelu(a.w + adj.w));
    }
  }
  #pragma unroll
  for (int m = 32; m >= 1; m >>= 1){
    m0 = fmaxf(m0, __shfl_xor(m0, m));
    m1 = fmaxf(m1, __shfl_xor(m1, m));
    m2 = fmaxf(m2, __shfl_xor(m2, m));
    m3 = fmaxf(m3, __shfl_xor(m3, m));
  }
  int hsel = lane >> 5;
  float mh0 = hsel ? m1 : m0;
  float mh1 = hsel ? m3 : m2;
  float adh0 = hsel ? adj.y : adj.x;
  float adh1 = hsel ? adj.w : adj.z;
  int c0 = lane, c1 = lane + 64;
  float acc0 = 0.f, acc1 = 0.f, den0 = 0.f, den1 = 0.f;
  for (int s = 0; s <= dg; ++s){
    int src = (s == dg) ? j : srcs[base + s];
    const float* ap = att + (size_t)src*8;
    float as0 = ap[hsel];
    float as1 = ap[2 + hsel];
    float w0 = __expf(lrelu(as0 + adh0) - mh0);
    float w1 = __expf(lrelu(as1 + adh1) - mh1);
    den0 += w0; den1 += w1;
    const float* hp = h + (size_t)src*HID;
    acc0 = fmaf(w0, hp[c0], acc0);
    acc1 = fmaf(w1, hp[c1], acc1);
  }
  float o0 = acc0/den0 + bias[c0];
  float o1 = acc1/den1 + bias[c1];
  float mean = wred_sum64(o0 + o1) * (1.f/HID);
  float d0 = o0 - mean, d1 = o1 - mean;
  float var = wred_sum64(d0*d0 + d1*d1) * (1.f/HID);
  float rs = rsqrtf(var + EPS);
  float r0 = fmaxf(fmaf(d0*rs, lng[c0], lnb[c0]), 0.f);
  float r1 = fmaxf(fmaf(d1*rs, lng[c1], lnb[c1]), 0.f);
  xo[(size_t)j*HID + c0] = r0;
  xo[(size_t)j*HID + c1] = r1;
}

// ---------------- heads: actor tanh(relu(xW1+b1)W2+b2), critic ----------------
__global__ __launch_bounds__(256) void heads_kernel(
    const float* __restrict__ x,
    const float* __restrict__ aW1, const float* __restrict__ ab1,
    const float* __restrict__ aW2, const float* __restrict__ ab2,
    const float* __restrict__ cW1, const float* __restrict__ cb1,
    const float* __restrict__ cW2, const float* __restrict__ cb2,
    float* __restrict__ out)
{
  __shared__ float xs[32][HID];
  int tid = threadIdx.x;
  int node0 = blockIdx.x * 32;
  for (int idx = tid; idx < 32*HID; idx += 256){
    int r = idx >> 7, c = idx & 127;
    xs[r][c] = x[(size_t)(node0 + r)*HID + c];
  }
  __syncthreads();
  int wave = tid >> 6, lane = tid & 63;
  int c0 = lane, c1 = lane + 64;
  float aacc[8][2], cacc[8][2];
  #pragma unroll
  for (int r = 0; r < 8; ++r){ aacc[r][0]=0.f; aacc[r][1]=0.f; cacc[r][0]=0.f; cacc[r][1]=0.f; }
  for (int k = 0; k < HID; ++k){
    float aw0 = aW1[k*HID + c0], aw1 = aW1[k*HID + c1];
    float cw0 = cW1[k*HID + c0], cw1 = cW1[k*HID + c1];
    #pragma unroll
    for (int r = 0; r < 8; ++r){
      float xv = xs[wave*8 + r][k];
      aacc[r][0] = fmaf(xv, aw0, aacc[r][0]);
      aacc[r][1] = fmaf(xv, aw1, aacc[r][1]);
      cacc[r][0] = fmaf(xv, cw0, cacc[r][0]);
      cacc[r][1] = fmaf(xv, cw1, cacc[r][1]);
    }
  }
  float ab1_0 = ab1[c0], ab1_1 = ab1[c1], cb1_0 = cb1[c0], cb1_1 = cb1[c1];
  float aw2_00 = aW2[c0*3+0], aw2_01 = aW2[c0*3+1], aw2_02 = aW2[c0*3+2];
  float aw2_10 = aW2[c1*3+0], aw2_11 = aW2[c1*3+1], aw2_12 = aW2[c1*3+2];
  float cw2_0 = cW2[c0], cw2_1 = cW2[c1];
  #pragma unroll
  for (int r = 0; r < 8; ++r){
    int n = node0 + wave*8 + r;
    float h0 = fmaxf(aacc[r][0] + ab1_0, 0.f);
    float h1 = fmaxf(aacc[r][1] + ab1_1, 0.f);
    float g0 = fmaxf(cacc[r][0] + cb1_0, 0.f);
    float g1 = fmaxf(cacc[r][1] + cb1_1, 0.f);
    float p0 = h0*aw2_00 + h1*aw2_10;
    float p1 = h0*aw2_01 + h1*aw2_11;
    float p2 = h0*aw2_02 + h1*aw2_12;
    float pv = g0*cw2_0 + g1*cw2_1;
    #pragma unroll
    for (int m = 32; m >= 1; m >>= 1){
      p0 += __shfl_xor(p0, m);
      p1 += __shfl_xor(p1, m);
      p2 += __shfl_xor(p2, m);
      pv += __shfl_xor(pv, m);
    }
    if (lane == 0){
      out[(size_t)n*3 + 0] = tanhf(p0 + ab2[0]);
      out[(size_t)n*3 + 1] = tanhf(p1 + ab2[1]);
      out[(size_t)n*3 + 2] = tanhf(p2 + ab2[2]);
      out[(size_t)BN*3 + n] = pv + cb2[0];
    }
  }
}

extern "C" void kernel_launch(void* const* d_in, const int* in_sizes, int n_in,
                              void* d_out, int out_size, void* d_ws, size_t ws_size,
                              hipStream_t stream) {
  const float* obs  = (const float*)d_in[0];
  const float* encW = (const float*)d_in[1];
  const float* encB = (const float*)d_in[2];
  const float* elng = (const float*)d_in[3];
  const float* elnb = (const float*)d_in[4];
  const float* temW = (const float*)d_in[5];
  const float* temB = (const float*)d_in[6];
  const float* aW1  = (const float*)d_in[7];
  const float* ab1  = (const float*)d_in[8];
  const float* aW2  = (const float*)d_in[9];
  const float* ab2  = (const float*)d_in[10];
  const float* cW1  = (const float*)d_in[11];
  const float* cb1  = (const float*)d_in[12];
  const float* cW2  = (const float*)d_in[13];
  const float* cb2  = (const float*)d_in[14];
  const float* gW[2]   = {(const float*)d_in[15], (const float*)d_in[21]};
  const float* gas[2]  = {(const float*)d_in[16], (const float*)d_in[22]};
  const float* gad[2]  = {(const float*)d_in[17], (const float*)d_in[23]};
  const float* gb[2]   = {(const float*)d_in[18], (const float*)d_in[24]};
  const float* glng[2] = {(const float*)d_in[19], (const float*)d_in[25]};
  const float* glnb[2] = {(const float*)d_in[20], (const float*)d_in[26]};

  float* x   = (float*)d_ws;
  float* h   = x + (size_t)BN*HID;
  float* att = h + (size_t)BN*HID;
  float4* pos4 = (float4*)(att + (size_t)BN*8);
  int* nbr    = (int*)(pos4 + BN);
  int* deg    = nbr + (size_t)BN*KK;
  int* cursor = deg + BN;
  int* offs   = cursor + BN;
  int* srcs   = offs + BN + 1;

  encoder_kernel<<<BN/4, 256, 0, stream>>>(obs, encW, encB, elng, elnb, temW, temB, x, pos4);
  knn_kernel<<<BN/16, 256, 0, stream>>>(pos4, nbr);
  zero_kernel<<<BN/256, 256, 0, stream>>>(deg, cursor);
  count_kernel<<<(BN*KK)/256, 256, 0, stream>>>(nbr, deg);
  scan_kernel<<<1, 1024, 0, stream>>>(deg, offs);
  scatter_kernel<<<(BN*KK)/256, 256, 0, stream>>>(nbr, offs, cursor, srcs);

  for (int l = 0; l < 2; ++l){
    gat_transform_kernel<<<BN/32, 256, 0, stream>>>(x, gW[l], gas[l], gad[l], h, att);
    gat_aggregate_kernel<<<BN/4, 256, 0, stream>>>(h, att, offs, deg, srcs,
                                                   gb[l], glng[l], glnb[l], x);
  }

  heads_kernel<<<BN/32, 256, 0, stream>>>(x, aW1, ab1, aW2, ab2, cW1, cb1, cW2, cb2,
                                          (float*)d_out);
}

// Round 16
// 519.229 us; speedup vs baseline: 2.2302x; 1.0874x over previous
//
#include <hip/hip_runtime.h>
#include <hip/hip_bf16.h>

#define BB 8
#define NN 4096
#define BN (BB*NN)
#define KK 10
#define HID 128
#define EPS 1e-5f
#define SLOPE 0.2f

__device__ __forceinline__ float wred_sum64(float v){
  #pragma unroll
  for (int m = 32; m >= 1; m >>= 1) v += __shfl_xor(v, m);
  return v;
}

__device__ __forceinline__ float lrelu(float v){ return v > 0.f ? v : SLOPE * v; }

// ---------------- encoder: x = LN(relu(phys@W+b))*g+b + silu(lat*temW+temb) ----
// also packs positions into pos4 (x,y,z,0) for the kNN kernel
__global__ __launch_bounds__(256) void encoder_kernel(
    const float* __restrict__ obs, const float* __restrict__ encW,
    const float* __restrict__ encB, const float* __restrict__ lng,
    const float* __restrict__ lnb, const float* __restrict__ temW,
    const float* __restrict__ temB, float* __restrict__ x,
    float4* __restrict__ pos4)
{
  int wave = threadIdx.x >> 6, lane = threadIdx.x & 63;
  int n = blockIdx.x * 4 + wave;
  const float* o = obs + (size_t)n * 10;
  float ph[9];
  #pragma unroll
  for (int k = 0; k < 9; ++k) ph[k] = o[k];
  float lat = o[9];
  if (lane == 0) pos4[n] = make_float4(ph[0], ph[1], ph[2], 0.f);
  int c0 = lane, c1 = lane + 64;
  float a0 = encB[c0], a1 = encB[c1];
  #pragma unroll
  for (int k = 0; k < 9; ++k){
    a0 = fmaf(ph[k], encW[k*HID + c0], a0);
    a1 = fmaf(ph[k], encW[k*HID + c1], a1);
  }
  a0 = fmaxf(a0, 0.f); a1 = fmaxf(a1, 0.f);
  float mean = wred_sum64(a0 + a1) * (1.f/HID);
  float d0 = a0 - mean, d1 = a1 - mean;
  float var = wred_sum64(d0*d0 + d1*d1) * (1.f/HID);
  float rs = rsqrtf(var + EPS);
  float r0 = d0*rs*lng[c0] + lnb[c0];
  float r1 = d1*rs*lng[c1] + lnb[c1];
  float z0 = fmaf(lat, temW[c0], temB[c0]);
  float z1 = fmaf(lat, temW[c1], temB[c1]);
  r0 += z0 / (1.f + __expf(-z0));
  r1 += z1 / (1.f + __expf(-z1));
  x[(size_t)n*HID + c0] = r0;
  x[(size_t)n*HID + c1] = r1;
}

// ---------------- kNN v4: two-pass (branchless value pass + exact index pass) -
// block = 256 thr = 16 nodes x 16 sublanes; 2 staged halves of 2048 candidates.
// Pass A: per-sublane top-10 DISTANCES via unconditional med3 insert (no branch,
//   ~12 VALU/step), fmaf distances; merge -> T = global 10th smallest (+2e-6 rel
//   inflation to cover fma-vs-rn rounding; sum of squares has no cancellation).
// Pass B: re-scan with reference-association rn distances; only d2<=T (~10/4096)
//   enter the exact u64 (d2,idx) sorted-insert network; robust u64 merge+write.
__global__ __launch_bounds__(256) void knn_kernel(
    const float4* __restrict__ pos4, int* __restrict__ nbr)
{
  __shared__ float4 X4[512], Y4[512], Z4[512];
  int bi = blockIdx.x;
  int b  = bi >> 8;           // 256 blocks per batch
  int nb = bi & 255;
  int tid = threadIdx.x;
  int g = tid >> 4, s = tid & 15;
  size_t boff = (size_t)b * NN;
  int i = nb * 16 + g;        // node index within batch
  float4 me = pos4[boff + i];
  float xi = me.x, yi = me.y, zi = me.z;

  // ---------------- pass A: branchless value-only top-10 ----------------
  float dk[KK];
  #pragma unroll
  for (int k = 0; k < KK; ++k) dk[k] = 3e38f;

  for (int h = 0; h < 2; ++h){
    __syncthreads();
    for (int p = tid; p < 512; p += 256){
      const float4* srcp = pos4 + boff + (size_t)(h*2048 + 4*p);
      float4 a = srcp[0], c = srcp[1], d = srcp[2], e = srcp[3];
      int slot = p ^ ((p >> 5) & 7);
      X4[slot] = make_float4(a.x, c.x, d.x, e.x);
      Y4[slot] = make_float4(a.y, c.y, d.y, e.y);
      Z4[slot] = make_float4(a.z, c.z, d.z, e.z);
    }
    __syncthreads();
    for (int q = 0; q < 32; ++q){
      int p = s * 32 + q;
      int slot = p ^ (s & 7);
      float4 X = X4[slot], Y = Y4[slot], Z = Z4[slot];
      int jb = h*2048 + (p << 2);
      #pragma unroll
      for (int cc = 0; cc < 4; ++cc){
        float cx = cc==0?X.x:cc==1?X.y:cc==2?X.z:X.w;
        float cy = cc==0?Y.x:cc==1?Y.y:cc==2?Y.z:Y.w;
        float cz = cc==0?Z.x:cc==1?Z.y:cc==2?Z.z:Z.w;
        int j = jb + cc;
        float dx = xi - cx, dy = yi - cy, dz = zi - cz;
        float c2 = fmaf(dz, dz, fmaf(dy, dy, dx*dx));
        c2 = (j == i) ? 3e38f : c2;            // exclude self
        // unconditional sorted insert: dk ascending; descending k reads old dk[k-1]
        #pragma unroll
        for (int k = KK-1; k >= 1; --k)
          dk[k] = fmaxf(dk[k-1], fminf(dk[k], c2));   // med3 pattern
        dk[0] = fminf(dk[0], c2);
      }
    }
  }

  // merge A across the 16-lane group: T >= exact global 10th smallest
  float T = 3e38f;
  for (int r = 0; r < KK; ++r){
    float k0 = dk[0];
    #pragma unroll
    for (int m = 1; m <= 8; m <<= 1) k0 = fminf(k0, __shfl_xor(k0, m));
    if (dk[0] == k0){        // all matching lanes pop (distinct candidates) -> T only grows
      #pragma unroll
      for (int k = 0; k < KK-1; ++k) dk[k] = dk[k+1];
      dk[KK-1] = 3e38f;
    }
    T = k0;
  }
  T = T * (1.f + 2e-6f);     // cover fma-vs-rn rounding skew (superset filter)

  // ---------------- pass B: exact (d2, idx) top-10 among d2<=T ----------------
  unsigned long long key[KK];
  #pragma unroll
  for (int k = 0; k < KK; ++k) key[k] = ~0ULL;

  for (int h = 0; h < 2; ++h){
    __syncthreads();
    for (int p = tid; p < 512; p += 256){
      const float4* srcp = pos4 + boff + (size_t)(h*2048 + 4*p);
      float4 a = srcp[0], c = srcp[1], d = srcp[2], e = srcp[3];
      int slot = p ^ ((p >> 5) & 7);
      X4[slot] = make_float4(a.x, c.x, d.x, e.x);
      Y4[slot] = make_float4(a.y, c.y, d.y, e.y);
      Z4[slot] = make_float4(a.z, c.z, d.z, e.z);
    }
    __syncthreads();
    for (int q = 0; q < 32; ++q){
      int p = s * 32 + q;
      int slot = p ^ (s & 7);
      float4 X = X4[slot], Y = Y4[slot], Z = Z4[slot];
      int jb = h*2048 + (p << 2);
      #pragma unroll
      for (int cc = 0; cc < 4; ++cc){
        float cx = cc==0?X.x:cc==1?X.y:cc==2?X.z:X.w;
        float cy = cc==0?Y.x:cc==1?Y.y:cc==2?Y.z:Y.w;
        float cz = cc==0?Z.x:cc==1?Z.y:cc==2?Z.z:Z.w;
        int j = jb + cc;
        float dx = __fsub_rn(xi, cx);
        float dy = __fsub_rn(yi, cy);
        float dz = __fsub_rn(zi, cz);
        // match XLA association, block FMA contraction
        float d2 = __fadd_rn(__fadd_rn(__fmul_rn(dx,dx), __fmul_rn(dy,dy)), __fmul_rn(dz,dz));
        if (d2 <= T && j != i){                 // rare: ~10 of 4096 candidates
          unsigned long long ck =
              ((unsigned long long)__float_as_uint(d2) << 32) | (unsigned)j;
          bool lt[KK];
          #pragma unroll
          for (int k = 0; k < KK; ++k) lt[k] = key[k] < ck;
          #pragma unroll
          for (int k = KK-1; k >= 1; --k)
            key[k] = lt[k] ? key[k] : (lt[k-1] ? ck : key[k-1]);
          key[0] = lt[0] ? key[0] : ck;
        }
      }
    }
  }

  // merge 16 sublane lists: 10 rounds of min-extract over the 16-lane group
  int gi = (int)boff + i;
  for (int r = 0; r < KK; ++r){
    unsigned long long k0 = key[0];
    #pragma unroll
    for (int m = 1; m <= 8; m <<= 1){
      unsigned long long ok = __shfl_xor(k0, m);
      if (ok < k0) k0 = ok;
    }
    if (key[0] == k0){   // unique winner: keys are unique (idx in low bits)
      #pragma unroll
      for (int k = 0; k < KK-1; ++k) key[k] = key[k+1];
      key[KK-1] = ~0ULL;
    }
    if (s == 0) nbr[(size_t)gi*KK + r] = (int)boff + (int)(unsigned)(k0 & 0xFFFFFFFFULL);
  }
}

// ---------------- CSR inversion --------------------------------------------
__global__ __launch_bounds__(256) void zero_kernel(int* __restrict__ a, int* __restrict__ b){
  int t = blockIdx.x * 256 + threadIdx.x;
  if (t < BN){ a[t] = 0; b[t] = 0; }
}

__global__ __launch_bounds__(256) void count_kernel(const int* __restrict__ nbr, int* __restrict__ deg){
  int t = blockIdx.x * 256 + threadIdx.x;
  if (t < BN*KK) atomicAdd(&deg[nbr[t]], 1);
}

__global__ __launch_bounds__(1024) void scan_kernel(const int* __restrict__ deg, int* __restrict__ offs){
  __shared__ int part[1024];
  int t = threadIdx.x;
  int base = t * 32;
  int loc[32];
  int s = 0;
  #pragma unroll
  for (int j = 0; j < 32; ++j){ loc[j] = s; s += deg[base + j]; }
  part[t] = s;
  __syncthreads();
  for (int off = 1; off < 1024; off <<= 1){
    int v = (t >= off) ? part[t - off] : 0;
    __syncthreads();
    part[t] += v;
    __syncthreads();
  }
  int prev = (t > 0) ? part[t-1] : 0;
  #pragma unroll
  for (int j = 0; j < 32; ++j) offs[base + j] = prev + loc[j];
  if (t == 1023) offs[BN] = part[1023];
}

__global__ __launch_bounds__(256) void scatter_kernel(
    const int* __restrict__ nbr, const int* __restrict__ offs,
    int* __restrict__ cursor, int* __restrict__ srcs)
{
  int t = blockIdx.x * 256 + threadIdx.x;
  if (t < BN*KK){
    int i = t / KK;
    int d = nbr[t];
    int p = atomicAdd(&cursor[d], 1);
    srcs[offs[d] + p] = i;
  }
}

// ---------------- GAT transform: h = x@W; as_/ad_ projections ----------------
__global__ __launch_bounds__(256) void gat_transform_kernel(
    const float* __restrict__ x, const float* __restrict__ W,
    const float* __restrict__ asrc, const float* __restrict__ adst,
    float* __restrict__ h, float* __restrict__ att)
{
  __shared__ float xs[32][HID];
  int tid = threadIdx.x;
  int node0 = blockIdx.x * 32;
  for (int idx = tid; idx < 32*HID; idx += 256){
    int r = idx >> 7, c = idx & 127;
    xs[r][c] = x[(size_t)(node0 + r)*HID + c];
  }
  __syncthreads();
  int wave = tid >> 6, lane = tid & 63;
  int c0 = lane, c1 = lane + 64;
  float acc[8][2];
  #pragma unroll
  for (int r = 0; r < 8; ++r){ acc[r][0] = 0.f; acc[r][1] = 0.f; }
  for (int k = 0; k < HID; ++k){
    float w0 = W[k*HID + c0], w1 = W[k*HID + c1];
    #pragma unroll
    for (int r = 0; r < 8; ++r){
      float xv = xs[wave*8 + r][k];
      acc[r][0] = fmaf(xv, w0, acc[r][0]);
      acc[r][1] = fmaf(xv, w1, acc[r][1]);
    }
  }
  float asc0 = asrc[c0], asc1 = asrc[c1], adc0 = adst[c0], adc1 = adst[c1];
  #pragma unroll
  for (int r = 0; r < 8; ++r){
    int n = node0 + wave*8 + r;
    float h0 = acc[r][0], h1 = acc[r][1];
    h[(size_t)n*HID + c0] = h0;
    h[(size_t)n*HID + c1] = h1;
    float pas0 = h0*asc0, pas1 = h1*asc1, pad0 = h0*adc0, pad1 = h1*adc1;
    #pragma unroll
    for (int m = 16; m >= 1; m >>= 1){
      pas0 += __shfl_xor(pas0, m); pas1 += __shfl_xor(pas1, m);
      pad0 += __shfl_xor(pad0, m); pad1 += __shfl_xor(pad1, m);
    }
    if ((lane & 31) == 0){
      int hd = lane >> 5;
      att[(size_t)n*8 + hd]     = pas0;   // as_ heads 0/1
      att[(size_t)n*8 + 2 + hd] = pas1;   // as_ heads 2/3
      att[(size_t)n*8 + 4 + hd] = pad0;   // ad_ heads 0/1
      att[(size_t)n*8 + 6 + hd] = pad1;   // ad_ heads 2/3
    }
  }
}

// ---------------- GAT aggregate + bias + LN + relu ---------------------------
__global__ __launch_bounds__(256) void gat_aggregate_kernel(
    const float* __restrict__ h, const float* __restrict__ att,
    const int* __restrict__ offs, const int* __restrict__ deg,
    const int* __restrict__ srcs, const float* __restrict__ bias,
    const float* __restrict__ lng, const float* __restrict__ lnb,
    float* __restrict__ xo)
{
  int wave = threadIdx.x >> 6, lane = threadIdx.x & 63;
  int j = blockIdx.x * 4 + wave;
  int dg = deg[j], base = offs[j];
  float4 adj = *(const float4*)(att + (size_t)j*8 + 4);
  // pass 1: per-head max over incoming edges + self loop (index dg)
  float m0 = -3e38f, m1 = -3e38f, m2 = -3e38f, m3 = -3e38f;
  for (int s0 = 0; s0 <= dg; s0 += 64){
    int s = s0 + lane;
    if (s <= dg){
      int src = (s == dg) ? j : srcs[base + s];
      float4 a = *(const float4*)(att + (size_t)src*8);
      m0 = fmaxf(m0, lrelu(a.x + adj.x));
      m1 = fmaxf(m1, lrelu(a.y + adj.y));
      m2 = fmaxf(m2, lrelu(a.z + adj.z));
      m3 = fmaxf(m3, lrelu(a.w + adj.w));
    }
  }
  #pragma unroll
  for (int m = 32; m >= 1; m >>= 1){
    m0 = fmaxf(m0, __shfl_xor(m0, m));
    m1 = fmaxf(m1, __shfl_xor(m1, m));
    m2 = fmaxf(m2, __shfl_xor(m2, m));
    m3 = fmaxf(m3, __shfl_xor(m3, m));
  }
  int hsel = lane >> 5;
  float mh0 = hsel ? m1 : m0;
  float mh1 = hsel ? m3 : m2;
  float adh0 = hsel ? adj.y : adj.x;
  float adh1 = hsel ? adj.w : adj.z;
  int c0 = lane, c1 = lane + 64;
  float acc0 = 0.f, acc1 = 0.f, den0 = 0.f, den1 = 0.f;
  for (int s = 0; s <= dg; ++s){
    int src = (s == dg) ? j : srcs[base + s];
    const float* ap = att + (size_t)src*8;
    float as0 = ap[hsel];
    float as1 = ap[2 + hsel];
    float w0 = __expf(lrelu(as0 + adh0) - mh0);
    float w1 = __expf(lrelu(as1 + adh1) - mh1);
    den0 += w0; den1 += w1;
    const float* hp = h + (size_t)src*HID;
    acc0 = fmaf(w0, hp[c0], acc0);
    acc1 = fmaf(w1, hp[c1], acc1);
  }
  float o0 = acc0/den0 + bias[c0];
  float o1 = acc1/den1 + bias[c1];
  float mean = wred_sum64(o0 + o1) * (1.f/HID);
  float d0 = o0 - mean, d1 = o1 - mean;
  float var = wred_sum64(d0*d0 + d1*d1) * (1.f/HID);
  float rs = rsqrtf(var + EPS);
  float r0 = fmaxf(fmaf(d0*rs, lng[c0], lnb[c0]), 0.f);
  float r1 = fmaxf(fmaf(d1*rs, lng[c1], lnb[c1]), 0.f);
  xo[(size_t)j*HID + c0] = r0;
  xo[(size_t)j*HID + c1] = r1;
}

// ---------------- heads: actor tanh(relu(xW1+b1)W2+b2), critic ----------------
__global__ __launch_bounds__(256) void heads_kernel(
    const float* __restrict__ x,
    const float* __restrict__ aW1, const float* __restrict__ ab1,
    const float* __restrict__ aW2, const float* __restrict__ ab2,
    const float* __restrict__ cW1, const float* __restrict__ cb1,
    const float* __restrict__ cW2, const float* __restrict__ cb2,
    float* __restrict__ out)
{
  __shared__ float xs[32][HID];
  int tid = threadIdx.x;
  int node0 = blockIdx.x * 32;
  for (int idx = tid; idx < 32*HID; idx += 256){
    int r = idx >> 7, c = idx & 127;
    xs[r][c] = x[(size_t)(node0 + r)*HID + c];
  }
  __syncthreads();
  int wave = tid >> 6, lane = tid & 63;
  int c0 = lane, c1 = lane + 64;
  float aacc[8][2], cacc[8][2];
  #pragma unroll
  for (int r = 0; r < 8; ++r){ aacc[r][0]=0.f; aacc[r][1]=0.f; cacc[r][0]=0.f; cacc[r][1]=0.f; }
  for (int k = 0; k < HID; ++k){
    float aw0 = aW1[k*HID + c0], aw1 = aW1[k*HID + c1];
    float cw0 = cW1[k*HID + c0], cw1 = cW1[k*HID + c1];
    #pragma unroll
    for (int r = 0; r < 8; ++r){
      float xv = xs[wave*8 + r][k];
      aacc[r][0] = fmaf(xv, aw0, aacc[r][0]);
      aacc[r][1] = fmaf(xv, aw1, aacc[r][1]);
      cacc[r][0] = fmaf(xv, cw0, cacc[r][0]);
      cacc[r][1] = fmaf(xv, cw1, cacc[r][1]);
    }
  }
  float ab1_0 = ab1[c0], ab1_1 = ab1[c1], cb1_0 = cb1[c0], cb1_1 = cb1[c1];
  float aw2_00 = aW2[c0*3+0], aw2_01 = aW2[c0*3+1], aw2_02 = aW2[c0*3+2];
  float aw2_10 = aW2[c1*3+0], aw2_11 = aW2[c1*3+1], aw2_12 = aW2[c1*3+2];
  float cw2_0 = cW2[c0], cw2_1 = cW2[c1];
  #pragma unroll
  for (int r = 0; r < 8; ++r){
    int n = node0 + wave*8 + r;
    float h0 = fmaxf(aacc[r][0] + ab1_0, 0.f);
    float h1 = fmaxf(aacc[r][1] + ab1_1, 0.f);
    float g0 = fmaxf(cacc[r][0] + cb1_0, 0.f);
    float g1 = fmaxf(cacc[r][1] + cb1_1, 0.f);
    float p0 = h0*aw2_00 + h1*aw2_10;
    float p1 = h0*aw2_01 + h1*aw2_11;
    float p2 = h0*aw2_02 + h1*aw2_12;
    float pv = g0*cw2_0 + g1*cw2_1;
    #pragma unroll
    for (int m = 32; m >= 1; m >>= 1){
      p0 += __shfl_xor(p0, m);
      p1 += __shfl_xor(p1, m);
      p2 += __shfl_xor(p2, m);
      pv += __shfl_xor(pv, m);
    }
    if (lane == 0){
      out[(size_t)n*3 + 0] = tanhf(p0 + ab2[0]);
      out[(size_t)n*3 + 1] = tanhf(p1 + ab2[1]);
      out[(size_t)n*3 + 2] = tanhf(p2 + ab2[2]);
      out[(size_t)BN*3 + n] = pv + cb2[0];
    }
  }
}

extern "C" void kernel_launch(void* const* d_in, const int* in_sizes, int n_in,
                              void* d_out, int out_size, void* d_ws, size_t ws_size,
                              hipStream_t stream) {
  const float* obs  = (const float*)d_in[0];
  const float* encW = (const float*)d_in[1];
  const float* encB = (const float*)d_in[2];
  const float* elng = (const float*)d_in[3];
  const float* elnb = (const float*)d_in[4];
  const float* temW = (const float*)d_in[5];
  const float* temB = (const float*)d_in[6];
  const float* aW1  = (const float*)d_in[7];
  const float* ab1  = (const float*)d_in[8];
  const float* aW2  = (const float*)d_in[9];
  const float* ab2  = (const float*)d_in[10];
  const float* cW1  = (const float*)d_in[11];
  const float* cb1  = (const float*)d_in[12];
  const float* cW2  = (const float*)d_in[13];
  const float* cb2  = (const float*)d_in[14];
  const float* gW[2]   = {(const float*)d_in[15], (const float*)d_in[21]};
  const float* gas[2]  = {(const float*)d_in[16], (const float*)d_in[22]};
  const float* gad[2]  = {(const float*)d_in[17], (const float*)d_in[23]};
  const float* gb[2]   = {(const float*)d_in[18], (const float*)d_in[24]};
  const float* glng[2] = {(const float*)d_in[19], (const float*)d_in[25]};
  const float* glnb[2] = {(const float*)d_in[20], (const float*)d_in[26]};

  float* x   = (float*)d_ws;
  float* h   = x + (size_t)BN*HID;
  float* att = h + (size_t)BN*HID;
  float4* pos4 = (float4*)(att + (size_t)BN*8);
  int* nbr    = (int*)(pos4 + BN);
  int* deg    = nbr + (size_t)BN*KK;
  int* cursor = deg + BN;
  int* offs   = cursor + BN;
  int* srcs   = offs + BN + 1;

  encoder_kernel<<<BN/4, 256, 0, stream>>>(obs, encW, encB, elng, elnb, temW, temB, x, pos4);
  knn_kernel<<<BN/16, 256, 0, stream>>>(pos4, nbr);
  zero_kernel<<<BN/256, 256, 0, stream>>>(deg, cursor);
  count_kernel<<<(BN*KK)/256, 256, 0, stream>>>(nbr, deg);
  scan_kernel<<<1, 1024, 0, stream>>>(deg, offs);
  scatter_kernel<<<(BN*KK)/256, 256, 0, stream>>>(nbr, offs, cursor, srcs);

  for (int l = 0; l < 2; ++l){
    gat_transform_kernel<<<BN/32, 256, 0, stream>>>(x, gW[l], gas[l], gad[l], h, att);
    gat_aggregate_kernel<<<BN/4, 256, 0, stream>>>(h, att, offs, deg, srcs,
                                                   gb[l], glng[l], glnb[l], x);
  }

  heads_kernel<<<BN/32, 256, 0, stream>>>(x, aW1, ab1, aW2, ab2, cW1, cb1, cW2, cb2,
                                          (float*)d_out);
}